// Round 1
// baseline (118.585 us; speedup 1.0000x reference)
//
#include <hip/hip_runtime.h>

// x: (16, 128, 256, 256) f32 ; out: (16, 128, 128, 128) f32
// out = sum(v * sp(v)) / sum(sp(v)) over each non-overlapping 2x2 patch,
// sp(v) = v > 10 ? v : log(1 + exp(v))   (softplus with threshold=10)

#define H 256
#define W 256
#define HO 128
#define WO 128

__device__ __forceinline__ float sp_thresh(float v) {
    // softplus with threshold 10; exp(v<=10) <= 22026, no overflow
    return v > 10.0f ? v : __logf(1.0f + __expf(v));
}

__global__ __launch_bounds__(256) void softpool2x2_kernel(
        const float* __restrict__ x, float* __restrict__ out, int npairs) {
    int idx = blockIdx.x * blockDim.x + threadIdx.x;
    if (idx >= npairs) return;

    // each thread computes 2 adjacent output pixels (one 4-col input span)
    int wp   = idx & (WO / 2 - 1);        // pair index along output width: 0..63
    int rest = idx >> 6;
    int ho   = rest & (HO - 1);           // 0..127
    int bc   = rest >> 7;                 // b*c plane: 0..2047

    const float* base = x + (size_t)bc * (H * W) + (size_t)(2 * ho) * W + wp * 4;
    float4 t = *reinterpret_cast<const float4*>(base);       // row 2i, cols 4wp..4wp+3
    float4 u = *reinterpret_cast<const float4*>(base + W);   // row 2i+1

    // patch 0: {t.x, t.y, u.x, u.y} ; patch 1: {t.z, t.w, u.z, u.w}
    float s0 = sp_thresh(t.x), s1 = sp_thresh(t.y);
    float s2 = sp_thresh(u.x), s3 = sp_thresh(u.y);
    float num0 = t.x * s0 + t.y * s1 + u.x * s2 + u.y * s3;
    float den0 = s0 + s1 + s2 + s3;

    float s4 = sp_thresh(t.z), s5 = sp_thresh(t.w);
    float s6 = sp_thresh(u.z), s7 = sp_thresh(u.w);
    float num1 = t.z * s4 + t.w * s5 + u.z * s6 + u.w * s7;
    float den1 = s4 + s5 + s6 + s7;

    float2 o;
    o.x = num0 / den0;   // softplus > 0, so den > 0 always
    o.y = num1 / den1;
    float* optr = out + (size_t)bc * (HO * WO) + (size_t)ho * WO + wp * 2;
    *reinterpret_cast<float2*>(optr) = o;
}

extern "C" void kernel_launch(void* const* d_in, const int* in_sizes, int n_in,
                              void* d_out, int out_size, void* d_ws, size_t ws_size,
                              hipStream_t stream) {
    const float* x = (const float*)d_in[0];
    float* out = (float*)d_out;
    // total output pairs: 16*128*128*64 = 16,777,216
    int npairs = out_size / 2;
    int block = 256;
    int grid = (npairs + block - 1) / block;   // 65536
    softpool2x2_kernel<<<grid, block, 0, stream>>>(x, out, npairs);
}

// Round 3
// 112.107 us; speedup vs baseline: 1.0578x; 1.0578x over previous
//
#include <hip/hip_runtime.h>

// x: (16, 128, 256, 256) f32 ; out: (16, 128, 128, 128) f32
// out = sum(v * sp(v)) / sum(sp(v)) over each non-overlapping 2x2 patch,
// sp(v) = v > 10 ? v : log(1 + exp(v))   (softplus with threshold=10)

#define H 256
#define W 256
#define HO 128
#define WO 128

typedef float fx4 __attribute__((ext_vector_type(4)));
typedef float fx2 __attribute__((ext_vector_type(2)));

__device__ __forceinline__ float sp_thresh(float v) {
    // softplus with threshold 10; exp(v<=10) <= 22026, no overflow
    return v > 10.0f ? v : __logf(1.0f + __expf(v));
}

__device__ __forceinline__ fx2 pool4(fx4 t, fx4 u) {
    // patch 0: {t[0], t[1], u[0], u[1]} ; patch 1: {t[2], t[3], u[2], u[3]}
    float s0 = sp_thresh(t[0]), s1 = sp_thresh(t[1]);
    float s2 = sp_thresh(u[0]), s3 = sp_thresh(u[1]);
    float num0 = t[0] * s0 + t[1] * s1 + u[0] * s2 + u[1] * s3;
    float den0 = s0 + s1 + s2 + s3;
    float s4 = sp_thresh(t[2]), s5 = sp_thresh(t[3]);
    float s6 = sp_thresh(u[2]), s7 = sp_thresh(u[3]);
    float num1 = t[2] * s4 + t[3] * s5 + u[2] * s6 + u[3] * s7;
    float den1 = s4 + s5 + s6 + s7;
    fx2 r;
    r[0] = num0 / den0;
    r[1] = num1 / den1;
    return r;
}

__global__ __launch_bounds__(256) void softpool2x2_kernel(
        const float* __restrict__ x, float* __restrict__ out) {
    int idx = blockIdx.x * blockDim.x + threadIdx.x;

    // each thread computes 4 adjacent output pixels (one 8-col input span, 2 rows)
    int wq   = idx & (WO / 4 - 1);        // quad index along output width: 0..31
    int rest = idx >> 5;
    int ho   = rest & (HO - 1);           // 0..127
    int bc   = rest >> 7;                 // b*c plane: 0..2047

    const fx4* r0 = reinterpret_cast<const fx4*>(
        x + (size_t)bc * (H * W) + (size_t)(2 * ho) * W + wq * 8);
    const fx4* r1 = reinterpret_cast<const fx4*>(
        reinterpret_cast<const float*>(r0) + W);

    // streaming reads: input is touched exactly once, bypass cache allocation
    fx4 t0 = __builtin_nontemporal_load(r0);
    fx4 t1 = __builtin_nontemporal_load(r0 + 1);
    fx4 u0 = __builtin_nontemporal_load(r1);
    fx4 u1 = __builtin_nontemporal_load(r1 + 1);

    fx2 a = pool4(t0, u0);
    fx2 b = pool4(t1, u1);
    fx4 o;
    o[0] = a[0]; o[1] = a[1]; o[2] = b[0]; o[3] = b[1];

    fx4* optr = reinterpret_cast<fx4*>(
        out + (size_t)bc * (HO * WO) + (size_t)ho * WO + wq * 4);
    __builtin_nontemporal_store(o, optr);
}

extern "C" void kernel_launch(void* const* d_in, const int* in_sizes, int n_in,
                              void* d_out, int out_size, void* d_ws, size_t ws_size,
                              hipStream_t stream) {
    const float* x = (const float*)d_in[0];
    float* out = (float*)d_out;
    // total threads: out_size / 4 = 16*128*128*32 = 8,388,608
    int nthreads = out_size / 4;
    int block = 256;
    int grid = nthreads / block;   // 32768, exact
    softpool2x2_kernel<<<grid, block, 0, stream>>>(x, out);
}